// Round 13
// baseline (1420.953 us; speedup 1.0000x reference)
//
#include <hip/hip_runtime.h>
#include <hip/hip_bf16.h>
#include <hip/hip_cooperative_groups.h>

namespace cg = cooperative_groups;

#define B_ 64
#define N_ 2048
#define I_ 16
#define J_ 32
#define O_ 32
#define JO_ 1024
#define WSF_NPW 16
#define SF_NPW 16

typedef __attribute__((ext_vector_type(8))) short bf16x8;
typedef __attribute__((ext_vector_type(16))) float f32x16;
typedef unsigned short u16;
typedef unsigned int u32;

__device__ __forceinline__ float bf2f(u16 u) {
  union { u32 i; float f; } c; c.i = ((u32)u) << 16; return c.f;
}
__device__ __forceinline__ u16 f2bf(float f) {
  union { float f; u32 i; } c; c.f = f;
  u32 r = (c.i + 0x7fffu + ((c.i >> 16) & 1u)) >> 16;
  return (u16)r;
}
__device__ __forceinline__ u32 pack2_pk(float lo, float hi) {
  u32 r;
  asm("v_cvt_pk_bf16_f32 %0, %1, %2" : "=v"(r) : "v"(lo), "v"(hi));
  return r;
}
__device__ __forceinline__ u32 scale2_pk(u32 p, float cv) {
  union { u32 i; float f; } lo, hi;
  lo.i = p << 16; hi.i = p & 0xffff0000u;
  return pack2_pk(lo.f * cv, hi.f * cv);
}
__device__ __forceinline__ float dot16(const f32x16& p, uint4 lo, uint4 hi) {
  const u32 w[8] = {lo.x, lo.y, lo.z, lo.w, hi.x, hi.y, hi.z, hi.w};
  float s = 0.f;
  #pragma unroll
  for (int k = 0; k < 8; ++k) {
    union { u32 i; float f; } a, b;
    a.i = w[k] << 16; b.i = w[k] & 0xffff0000u;
    s += p[2 * k] * a.f + p[2 * k + 1] * b.f;
  }
  return s;
}

// ---------------------------------------------------------------------------
// Phase bodies (shared by mega kernel and fallback kernels). All are the
// round-8-verified implementations, only re-indexed by an explicit bid.
// ---------------------------------------------------------------------------
__device__ __forceinline__ void xconv_item(
    const float* __restrict__ xf, u16* __restrict__ xt, int idx)
{
  const int b = idx >> 11, n = idx & 2047;
  const float4* sp = (const float4*)(xf + (size_t)idx * 16);
  float4 f0 = sp[0], f1 = sp[1], f2 = sp[2], f3 = sp[3];
  uint4 d0, d1;
  d0.x = pack2_pk(f0.x, f0.y); d0.y = pack2_pk(f0.z, f0.w);
  d0.z = pack2_pk(f1.x, f1.y); d0.w = pack2_pk(f1.z, f1.w);
  d1.x = pack2_pk(f2.x, f2.y); d1.y = pack2_pk(f2.z, f2.w);
  d1.z = pack2_pk(f3.x, f3.y); d1.w = pack2_pk(f3.z, f3.w);
  uint4* dp = (uint4*)(xt + ((size_t)n * 64 + b) * 16);
  dp[0] = d0; dp[1] = d1;
}

// wconv + sf iter-0 (uniform c). bid in [0,1024): j = bid>>5, split = bid&31.
__device__ __forceinline__ void wsf_body(
    const float* __restrict__ wf, u16* __restrict__ wb,
    const u16* __restrict__ xt, float* __restrict__ s_part,
    float (*red)[2048], int bid, int tid)
{
  const int wave = tid >> 6, lane = tid & 63;
  const int l31 = lane & 31, h = lane >> 5;
  const int j = bid >> 5, split = bid & 31;
  const int n0 = (split * 4 + wave) * WSF_NPW;
  f32x16 acc0 = {0.f, 0.f, 0.f, 0.f, 0.f, 0.f, 0.f, 0.f,
                 0.f, 0.f, 0.f, 0.f, 0.f, 0.f, 0.f, 0.f};
  f32x16 acc1 = acc0;
  #pragma unroll 4
  for (int i = 0; i < WSF_NPW; ++i) {
    const int n = n0 + i;
    const size_t row = (size_t)n * JO_ + j * 32 + l31;
    const float* wsrc = wf + row * 16 + h * 8;
    const float4 f0 = *(const float4*)(wsrc);
    const float4 f1 = *(const float4*)(wsrc + 4);
    union { uint4 u4; bf16x8 bv; } wd;
    wd.u4.x = pack2_pk(f0.x, f0.y); wd.u4.y = pack2_pk(f0.z, f0.w);
    wd.u4.z = pack2_pk(f1.x, f1.y); wd.u4.w = pack2_pk(f1.z, f1.w);
    *(uint4*)(wb + row * 16 + h * 8) = wd.u4;
    const bf16x8 x0 = *(const bf16x8*)(xt + ((size_t)n * 64 + l31) * 16 + h * 8);
    const bf16x8 x1 = *(const bf16x8*)(xt + ((size_t)n * 64 + 32 + l31) * 16 + h * 8);
    acc0 = __builtin_amdgcn_mfma_f32_32x32x16_bf16(wd.bv, x0, acc0, 0, 0, 0);
    acc1 = __builtin_amdgcn_mfma_f32_32x32x16_bf16(wd.bv, x1, acc1, 0, 0, 0);
  }
  #pragma unroll
  for (int r = 0; r < 16; ++r) {
    const int o = (r & 3) + 8 * (r >> 2) + 4 * h;
    red[wave][o * 64 + l31] = acc0[r];
    red[wave][o * 64 + 32 + l31] = acc1[r];
  }
  __syncthreads();
  float* dst = s_part + (size_t)split * (JO_ * B_) + (size_t)j * 32 * 64;
  #pragma unroll
  for (int k = 0; k < 8; ++k) {
    const int idx = tid + 256 * k;
    dst[idx] = red[0][idx] + red[1][idx] + red[2][idx] + red[3][idx];
  }
  __syncthreads();
}

// agreement for one n (round-8 a_kernel). lgs = 64*33 floats of LDS.
__device__ __forceinline__ void a_body(
    const u16* __restrict__ xt, const u16* __restrict__ wb,
    const u16* __restrict__ v4, u16* __restrict__ ct,
    float* lgs, int n, int tid)
{
  const int wave = tid >> 6, lane = tid & 63;
  const int l31 = lane & 31, h = lane >> 5;
  const f32x16 zero16 = {0.f, 0.f, 0.f, 0.f, 0.f, 0.f, 0.f, 0.f,
                         0.f, 0.f, 0.f, 0.f, 0.f, 0.f, 0.f, 0.f};
  const bf16x8 x0 = *(const bf16x8*)(xt + ((size_t)n * 64 + l31) * 16 + h * 8);
  const bf16x8 x1 = *(const bf16x8*)(xt + ((size_t)n * 64 + 32 + l31) * 16 + h * 8);
  {
    const int t0 = wave * 8;
    bf16x8 wfr = *(const bf16x8*)(wb + ((size_t)n * JO_ + t0 * 32 + l31) * 16 + h * 8);
    const u16* pa = v4 + (((size_t)t0 * 2 + h) * 64 + l31) * 16;
    const u16* pb = v4 + (((size_t)t0 * 2 + h) * 64 + 32 + l31) * 16;
    uint4 va0 = *(const uint4*)(pa), va1 = *(const uint4*)(pa + 8);
    uint4 vb0 = *(const uint4*)(pb), vb1 = *(const uint4*)(pb + 8);
    #pragma unroll 1
    for (int tt = 0; tt < 8; ++tt) {
      const int t = wave * 8 + tt;
      bf16x8 wfr_n = wfr;
      uint4 va0n = va0, va1n = va1, vb0n = vb0, vb1n = vb1;
      if (tt + 1 < 8) {
        const int t1 = t + 1;
        wfr_n = *(const bf16x8*)(wb + ((size_t)n * JO_ + t1 * 32 + l31) * 16 + h * 8);
        const u16* qa = v4 + (((size_t)t1 * 2 + h) * 64 + l31) * 16;
        const u16* qb = v4 + (((size_t)t1 * 2 + h) * 64 + 32 + l31) * 16;
        va0n = *(const uint4*)(qa); va1n = *(const uint4*)(qa + 8);
        vb0n = *(const uint4*)(qb); vb1n = *(const uint4*)(qb + 8);
      }
      f32x16 p0 = __builtin_amdgcn_mfma_f32_32x32x16_bf16(wfr, x0, zero16, 0, 0, 0);
      f32x16 p1 = __builtin_amdgcn_mfma_f32_32x32x16_bf16(wfr, x1, zero16, 0, 0, 0);
      float s0 = dot16(p0, va0, va1);
      float s1 = dot16(p1, vb0, vb1);
      s0 += __shfl_xor(s0, 32, 64);
      s1 += __shfl_xor(s1, 32, 64);
      lgs[lane * 33 + t] = h ? s1 : s0;
      wfr = wfr_n; va0 = va0n; va1 = va1n; vb0 = vb0n; vb1 = vb1n;
    }
  }
  __syncthreads();
  if (tid < 64) {
    const int b = tid;
    float lv[32];
    float mx = -1e30f;
    #pragma unroll
    for (int t = 0; t < 32; ++t) { lv[t] = lgs[b * 33 + t]; mx = fmaxf(mx, lv[t]); }
    float sm = 0.f;
    #pragma unroll
    for (int t = 0; t < 32; ++t) { lv[t] = __expf(lv[t] - mx); sm += lv[t]; }
    const float inv = 1.f / sm;
    #pragma unroll
    for (int t = 0; t < 32; ++t) lgs[b * 33 + t] = lv[t] * inv;
  }
  __syncthreads();
  #pragma unroll
  for (int k = 0; k < 8; ++k) {
    const int idx = k * 256 + tid;
    const int t = idx >> 6, b = idx & 63;
    ct[((size_t)t * N_ + n) * 64 + b] = f2bf(lgs[b * 33 + t]);
  }
  __syncthreads();
}

// sf iters 1,2 (round-8 sf_kernel, 1-deep pipeline). bid in [0,1024).
__device__ __forceinline__ void sf_body(
    const u16* __restrict__ xt, const u16* __restrict__ wb,
    const u16* __restrict__ ct, float* __restrict__ s_part,
    float (*red)[2048], int bid, int tid)
{
  const int wave = tid >> 6, lane = tid & 63;
  const int l31 = lane & 31, h = lane >> 5;
  const int j = bid >> 5, split = bid & 31;
  const int n0 = (split * 4 + wave) * SF_NPW;
  f32x16 acc0 = {0.f, 0.f, 0.f, 0.f, 0.f, 0.f, 0.f, 0.f,
                 0.f, 0.f, 0.f, 0.f, 0.f, 0.f, 0.f, 0.f};
  f32x16 acc1 = acc0;

  bf16x8 wfr = *(const bf16x8*)(wb + ((size_t)n0 * JO_ + j * 32 + l31) * 16 + h * 8);
  union { bf16x8 v_; u32 u[4]; } xa, xb;
  xa.v_ = *(const bf16x8*)(xt + ((size_t)n0 * 64 + l31) * 16 + h * 8);
  xb.v_ = *(const bf16x8*)(xt + ((size_t)n0 * 64 + 32 + l31) * 16 + h * 8);
  float cv0 = bf2f(ct[((size_t)j * N_ + n0) * 64 + l31]);
  float cv1 = bf2f(ct[((size_t)j * N_ + n0) * 64 + 32 + l31]);

  #pragma unroll 1
  for (int i = 0; i < SF_NPW; ++i) {
    bf16x8 wfr_n = wfr;
    union { bf16x8 v_; u32 u[4]; } xa_n, xb_n;
    xa_n.v_ = xa.v_; xb_n.v_ = xb.v_;
    float c0n = cv0, c1n = cv1;
    if (i + 1 < SF_NPW) {
      const int n1 = n0 + i + 1;
      wfr_n = *(const bf16x8*)(wb + ((size_t)n1 * JO_ + j * 32 + l31) * 16 + h * 8);
      xa_n.v_ = *(const bf16x8*)(xt + ((size_t)n1 * 64 + l31) * 16 + h * 8);
      xb_n.v_ = *(const bf16x8*)(xt + ((size_t)n1 * 64 + 32 + l31) * 16 + h * 8);
      c0n = bf2f(ct[((size_t)j * N_ + n1) * 64 + l31]);
      c1n = bf2f(ct[((size_t)j * N_ + n1) * 64 + 32 + l31]);
    }
    union { bf16x8 v_; u32 u[4]; } s0, s1;
    s0.u[0] = scale2_pk(xa.u[0], cv0); s0.u[1] = scale2_pk(xa.u[1], cv0);
    s0.u[2] = scale2_pk(xa.u[2], cv0); s0.u[3] = scale2_pk(xa.u[3], cv0);
    s1.u[0] = scale2_pk(xb.u[0], cv1); s1.u[1] = scale2_pk(xb.u[1], cv1);
    s1.u[2] = scale2_pk(xb.u[2], cv1); s1.u[3] = scale2_pk(xb.u[3], cv1);
    acc0 = __builtin_amdgcn_mfma_f32_32x32x16_bf16(wfr, s0.v_, acc0, 0, 0, 0);
    acc1 = __builtin_amdgcn_mfma_f32_32x32x16_bf16(wfr, s1.v_, acc1, 0, 0, 0);
    wfr = wfr_n; xa.v_ = xa_n.v_; xb.v_ = xb_n.v_; cv0 = c0n; cv1 = c1n;
  }
  #pragma unroll
  for (int r = 0; r < 16; ++r) {
    const int o = (r & 3) + 8 * (r >> 2) + 4 * h;
    red[wave][o * 64 + l31] = acc0[r];
    red[wave][o * 64 + 32 + l31] = acc1[r];
  }
  __syncthreads();
  float* dst = s_part + (size_t)split * (JO_ * B_) + (size_t)j * 32 * 64;
  #pragma unroll
  for (int k = 0; k < 8; ++k) {
    const int idx = tid + 256 * k;
    dst[idx] = red[0][idx] + red[1][idx] + red[2][idx] + red[3][idx];
  }
  __syncthreads();
}

// squash: one (b,j) per wave; h-halves split the 32 splits; no atomics.
__device__ __forceinline__ void squash_body(
    const float* __restrict__ s_part, float* __restrict__ v,
    u16* __restrict__ v4, float* __restrict__ out,
    int mode, float scale, int wid, int tid)
{
  const int lane = tid & 63;
  const int l31 = lane & 31, h = lane >> 5;
  if (wid < 2048) {
    const int j = wid & 31, b = wid >> 5;
    const int o = l31;
    float s = 0.f;
    const float* sp = s_part + (size_t)(j * 32 + o) * 64 + b
                    + (size_t)(h ? 16 : 0) * (JO_ * B_);
    #pragma unroll
    for (int k = 0; k < 16; ++k) s += sp[(size_t)k * (JO_ * B_)];
    float st = (s + __shfl_xor(s, 32, 64)) * scale;
    float sq = st * st;
    #pragma unroll
    for (int m = 16; m >= 1; m >>= 1) sq += __shfl_xor(sq, m, 64);
    const float sc = sq / (1.f + sq) * rsqrtf(sq + 1e-8f);
    const float vv = sc * st;
    if (h == 0) {
      const size_t off = (size_t)b * JO_ + j * 32 + o;
      const int g = o >> 3, hh = (o >> 2) & 1, rr = o & 3;
      const size_t v4off = (((size_t)j * 2 + hh) * 64 + b) * 16 + g * 4 + rr;
      if (mode == 0)      { v[off] = vv; v4[v4off] = f2bf(vv); }
      else if (mode == 1) { v4[v4off] = f2bf(vv + v[off]); }
      else                { out[off] = vv; }
    }
  }
}

// ---------------------------------------------------------------------------
// MEGA kernel: one cooperative launch, grid 512 (2 blocks/CU — 2x headroom
// under the 4/CU occupancy limit; round-12's 1024 = exact max likely failed
// launch validation). __threadfence() around every grid.sync() = device-scope
// release/acquire insurance for cross-XCD L2 (workspace is re-poisoned
// between runs; stale poison lines in a reader XCD's L2 would corrupt).
// ---------------------------------------------------------------------------
#define GSYNC() do { __threadfence(); grid.sync(); __threadfence(); } while (0)

__global__ __launch_bounds__(256, 4) void mega_kernel(
    const float* __restrict__ xf, const float* __restrict__ wf,
    float* __restrict__ out, char* __restrict__ ws)
{
  u16*   wb     = (u16*)ws;
  u16*   xt     = (u16*)(ws + (size_t)64 * 1024 * 1024);
  float* s_part = (float*)(ws + (size_t)68 * 1024 * 1024);
  float* v0     = (float*)(ws + (size_t)76 * 1024 * 1024);
  u16*   v4     = (u16*)(ws + (size_t)76 * 1024 * 1024 + 262144);
  u16*   ct     = (u16*)(ws + (size_t)78 * 1024 * 1024);

  __shared__ float red[4][2048];   // 32 KB, reused by every phase
  cg::grid_group grid = cg::this_grid();
  const int bid = blockIdx.x, tid = threadIdx.x;
  const int wave = tid >> 6;

  // xconv: 131072 items over 512*256 threads (exact)
  xconv_item(xf, xt, bid * 256 + tid);
  GSYNC();
  // wconv + sf iter-0
  #pragma unroll 1
  for (int sub = 0; sub < 2; ++sub)
    wsf_body(wf, wb, xt, s_part, red, sub * 512 + bid, tid);
  GSYNC();
  squash_body(s_part, v0, v4, out, 0, 0.03125f, bid * 4 + wave, tid);
  GSYNC();
  // iter 1
  #pragma unroll 1
  for (int nn = 0; nn < 4; ++nn)
    a_body(xt, wb, v4, ct, &red[0][0], bid * 4 + nn, tid);
  GSYNC();
  #pragma unroll 1
  for (int sub = 0; sub < 2; ++sub)
    sf_body(xt, wb, ct, s_part, red, sub * 512 + bid, tid);
  GSYNC();
  squash_body(s_part, v0, v4, out, 1, 1.0f, bid * 4 + wave, tid);
  GSYNC();
  // iter 2
  #pragma unroll 1
  for (int nn = 0; nn < 4; ++nn)
    a_body(xt, wb, v4, ct, &red[0][0], bid * 4 + nn, tid);
  GSYNC();
  #pragma unroll 1
  for (int sub = 0; sub < 2; ++sub)
    sf_body(xt, wb, ct, s_part, red, sub * 512 + bid, tid);
  GSYNC();
  squash_body(s_part, v0, v4, out, 2, 1.0f, bid * 4 + wave, tid);
}

// ---------------------------------------------------------------------------
// Fallback kernels (9-launch pipeline; used if cooperative launch fails).
// ---------------------------------------------------------------------------
__global__ __launch_bounds__(256) void xconv_kernel(
    const float* __restrict__ xf, u16* __restrict__ xt)
{
  xconv_item(xf, xt, blockIdx.x * 256 + threadIdx.x);
}

__global__ __launch_bounds__(256, 4) void wsf_kernel(
    const float* __restrict__ wf, u16* __restrict__ wb,
    const u16* __restrict__ xt, float* __restrict__ s_part)
{
  __shared__ float red[4][2048];
  wsf_body(wf, wb, xt, s_part, red, blockIdx.x, threadIdx.x);
}

__global__ __launch_bounds__(256, 4) void a_kernel(
    const u16* __restrict__ xt, const u16* __restrict__ wb,
    const u16* __restrict__ v4, u16* __restrict__ ct)
{
  __shared__ float lgs[64 * 33];
  a_body(xt, wb, v4, ct, lgs, blockIdx.x, threadIdx.x);
}

__global__ __launch_bounds__(256, 4) void sf_kernel(
    const u16* __restrict__ xt, const u16* __restrict__ wb,
    const u16* __restrict__ ct, float* __restrict__ s_part)
{
  __shared__ float red[4][2048];
  sf_body(xt, wb, ct, s_part, red, blockIdx.x, threadIdx.x);
}

__global__ __launch_bounds__(256) void squash_kernel(
    const float* __restrict__ s_part, float* __restrict__ v,
    u16* __restrict__ v4, float* __restrict__ out, int mode, float scale)
{
  squash_body(s_part, v, v4, out, mode, scale,
              blockIdx.x * 4 + (threadIdx.x >> 6), threadIdx.x);
}

// ---------------------------------------------------------------------------
extern "C" void kernel_launch(void* const* d_in, const int* in_sizes, int n_in,
                              void* d_out, int out_size, void* d_ws, size_t ws_size,
                              hipStream_t stream) {
  const float* x = (const float*)d_in[0];
  const float* w = (const float*)d_in[1];
  float* out = (float*)d_out;
  char* ws = (char*)d_ws;

  void* args[] = {(void*)&x, (void*)&w, (void*)&out, (void*)&ws};
  hipError_t err = hipLaunchCooperativeKernel(
      (const void*)mega_kernel, dim3(512), dim3(256), args, 0, stream);
  if (err != hipSuccess) {
    // fallback: 9-launch pipeline (round-8 structure, rs+r -> squash)
    u16*   wb     = (u16*)ws;
    u16*   xt     = (u16*)(ws + (size_t)64 * 1024 * 1024);
    float* s_part = (float*)(ws + (size_t)68 * 1024 * 1024);
    float* v0     = (float*)(ws + (size_t)76 * 1024 * 1024);
    u16*   v4     = (u16*)(ws + (size_t)76 * 1024 * 1024 + 262144);
    u16*   ct     = (u16*)(ws + (size_t)78 * 1024 * 1024);
    xconv_kernel<<<dim3(512), dim3(256), 0, stream>>>(x, xt);
    wsf_kernel<<<dim3(1024), dim3(256), 0, stream>>>(w, wb, xt, s_part);
    squash_kernel<<<dim3(512), dim3(256), 0, stream>>>(s_part, v0, v4, out, 0, 0.03125f);
    a_kernel<<<dim3(2048), dim3(256), 0, stream>>>(xt, wb, v4, ct);
    sf_kernel<<<dim3(1024), dim3(256), 0, stream>>>(xt, wb, ct, s_part);
    squash_kernel<<<dim3(512), dim3(256), 0, stream>>>(s_part, v0, v4, out, 1, 1.0f);
    a_kernel<<<dim3(2048), dim3(256), 0, stream>>>(xt, wb, v4, ct);
    sf_kernel<<<dim3(1024), dim3(256), 0, stream>>>(xt, wb, ct, s_part);
    squash_kernel<<<dim3(512), dim3(256), 0, stream>>>(s_part, v0, v4, out, 2, 1.0f);
  }
}

// Round 14
// 346.082 us; speedup vs baseline: 4.1058x; 4.1058x over previous
//
#include <hip/hip_runtime.h>
#include <hip/hip_bf16.h>

#define B_ 64
#define N_ 2048
#define I_ 16
#define J_ 32
#define O_ 32
#define JO_ 1024
#define WSPLITS 32
#define SFSPLITS 64
#define WSF_NPW 16
#define SF_NPW 8

typedef __attribute__((ext_vector_type(8))) short bf16x8;
typedef __attribute__((ext_vector_type(16))) float f32x16;
typedef unsigned short u16;
typedef unsigned int u32;

__device__ __forceinline__ float bf2f(u16 u) {
  union { u32 i; float f; } c; c.i = ((u32)u) << 16; return c.f;
}
__device__ __forceinline__ u16 f2bf(float f) {
  union { float f; u32 i; } c; c.f = f;
  u32 r = (c.i + 0x7fffu + ((c.i >> 16) & 1u)) >> 16;
  return (u16)r;
}
__device__ __forceinline__ u32 pack2_pk(float lo, float hi) {
  u32 r;
  asm("v_cvt_pk_bf16_f32 %0, %1, %2" : "=v"(r) : "v"(lo), "v"(hi));
  return r;
}
__device__ __forceinline__ u32 scale2_pk(u32 p, float cv) {
  union { u32 i; float f; } lo, hi;
  lo.i = p << 16; hi.i = p & 0xffff0000u;
  return pack2_pk(lo.f * cv, hi.f * cv);
}
__device__ __forceinline__ float dot16(const f32x16& p, uint4 lo, uint4 hi) {
  const u32 w[8] = {lo.x, lo.y, lo.z, lo.w, hi.x, hi.y, hi.z, hi.w};
  float s = 0.f;
  #pragma unroll
  for (int k = 0; k < 8; ++k) {
    union { u32 i; float f; } a, b;
    a.i = w[k] << 16; b.i = w[k] & 0xffff0000u;
    s += p[2 * k] * a.f + p[2 * k + 1] * b.f;
  }
  return s;
}

// ---------------------------------------------------------------------------
// xconv: x f32 [b][n][i] -> xt bf16 [n][b][i]
// ---------------------------------------------------------------------------
__global__ __launch_bounds__(256) void xconv_kernel(
    const float* __restrict__ xf, u16* __restrict__ xt)
{
  const int idx = blockIdx.x * 256 + threadIdx.x;
  const int b = idx >> 11, n = idx & 2047;
  const float4* sp = (const float4*)(xf + (size_t)idx * 16);
  float4 f0 = sp[0], f1 = sp[1], f2 = sp[2], f3 = sp[3];
  uint4 d0, d1;
  d0.x = pack2_pk(f0.x, f0.y); d0.y = pack2_pk(f0.z, f0.w);
  d0.z = pack2_pk(f1.x, f1.y); d0.w = pack2_pk(f1.z, f1.w);
  d1.x = pack2_pk(f2.x, f2.y); d1.y = pack2_pk(f2.z, f2.w);
  d1.z = pack2_pk(f3.x, f3.y); d1.w = pack2_pk(f3.z, f3.w);
  uint4* dp = (uint4*)(xt + ((size_t)n * 64 + b) * 16);
  dp[0] = d0; dp[1] = d1;
}

// ---------------------------------------------------------------------------
// WSF: fused wconv + sf iter-0 (uniform c). Round-8 verbatim.
// grid (32 j, 32 split), block 256, partials to s_part32.
// ---------------------------------------------------------------------------
__global__ __launch_bounds__(256, 4) void wsf_kernel(
    const float* __restrict__ wf, u16* __restrict__ wb,
    const u16* __restrict__ xt, float* __restrict__ s_part)
{
  __shared__ float red[4][2048];   // 32 KB
  const int tid = threadIdx.x;
  const int wave = tid >> 6, lane = tid & 63;
  const int l31 = lane & 31, h = lane >> 5;
  const int j = blockIdx.x, split = blockIdx.y;
  const int n0 = (split * 4 + wave) * WSF_NPW;
  f32x16 acc0 = {0.f, 0.f, 0.f, 0.f, 0.f, 0.f, 0.f, 0.f,
                 0.f, 0.f, 0.f, 0.f, 0.f, 0.f, 0.f, 0.f};
  f32x16 acc1 = acc0;

  #pragma unroll 4
  for (int i = 0; i < WSF_NPW; ++i) {
    const int n = n0 + i;
    const size_t row = (size_t)n * JO_ + j * 32 + l31;
    const float* wsrc = wf + row * 16 + h * 8;
    const float4 f0 = *(const float4*)(wsrc);
    const float4 f1 = *(const float4*)(wsrc + 4);
    union { uint4 u4; bf16x8 bv; } wd;
    wd.u4.x = pack2_pk(f0.x, f0.y); wd.u4.y = pack2_pk(f0.z, f0.w);
    wd.u4.z = pack2_pk(f1.x, f1.y); wd.u4.w = pack2_pk(f1.z, f1.w);
    *(uint4*)(wb + row * 16 + h * 8) = wd.u4;   // persist for a/sf passes
    const bf16x8 x0 = *(const bf16x8*)(xt + ((size_t)n * 64 + l31) * 16 + h * 8);
    const bf16x8 x1 = *(const bf16x8*)(xt + ((size_t)n * 64 + 32 + l31) * 16 + h * 8);
    acc0 = __builtin_amdgcn_mfma_f32_32x32x16_bf16(wd.bv, x0, acc0, 0, 0, 0);
    acc1 = __builtin_amdgcn_mfma_f32_32x32x16_bf16(wd.bv, x1, acc1, 0, 0, 0);
  }
  #pragma unroll
  for (int r = 0; r < 16; ++r) {
    const int o = (r & 3) + 8 * (r >> 2) + 4 * h;
    red[wave][o * 64 + l31] = acc0[r];
    red[wave][o * 64 + 32 + l31] = acc1[r];
  }
  __syncthreads();
  float* dst = s_part + (size_t)split * (JO_ * B_) + (size_t)j * 32 * 64;
  #pragma unroll
  for (int k = 0; k < 8; ++k) {
    const int idx = tid + 256 * k;
    dst[idx] = red[0][idx] + red[1][idx] + red[2][idx] + red[3][idx];
  }
}

// ---------------------------------------------------------------------------
// SF (iters 1,2): round-8 verbatim — 1-deep rotation, unroll 1, 64 splits.
// ---------------------------------------------------------------------------
__global__ __launch_bounds__(256, 4) void sf_kernel(
    const u16* __restrict__ xt, const u16* __restrict__ wb,
    const u16* __restrict__ ct, float* __restrict__ s_part)
{
  __shared__ float red[4][2048];
  const int tid = threadIdx.x;
  const int wave = tid >> 6, lane = tid & 63;
  const int l31 = lane & 31, h = lane >> 5;
  const int j = blockIdx.x, split = blockIdx.y;
  const int n0 = (split * 4 + wave) * SF_NPW;
  f32x16 acc0 = {0.f, 0.f, 0.f, 0.f, 0.f, 0.f, 0.f, 0.f,
                 0.f, 0.f, 0.f, 0.f, 0.f, 0.f, 0.f, 0.f};
  f32x16 acc1 = acc0;

  bf16x8 wfr = *(const bf16x8*)(wb + ((size_t)n0 * JO_ + j * 32 + l31) * 16 + h * 8);
  union { bf16x8 v_; u32 u[4]; } xa, xb;
  xa.v_ = *(const bf16x8*)(xt + ((size_t)n0 * 64 + l31) * 16 + h * 8);
  xb.v_ = *(const bf16x8*)(xt + ((size_t)n0 * 64 + 32 + l31) * 16 + h * 8);
  float cv0 = bf2f(ct[((size_t)j * N_ + n0) * 64 + l31]);
  float cv1 = bf2f(ct[((size_t)j * N_ + n0) * 64 + 32 + l31]);

  #pragma unroll 1
  for (int i = 0; i < SF_NPW; ++i) {
    bf16x8 wfr_n = wfr;
    union { bf16x8 v_; u32 u[4]; } xa_n, xb_n;
    xa_n.v_ = xa.v_; xb_n.v_ = xb.v_;
    float c0n = cv0, c1n = cv1;
    if (i + 1 < SF_NPW) {
      const int n1 = n0 + i + 1;
      wfr_n = *(const bf16x8*)(wb + ((size_t)n1 * JO_ + j * 32 + l31) * 16 + h * 8);
      xa_n.v_ = *(const bf16x8*)(xt + ((size_t)n1 * 64 + l31) * 16 + h * 8);
      xb_n.v_ = *(const bf16x8*)(xt + ((size_t)n1 * 64 + 32 + l31) * 16 + h * 8);
      c0n = bf2f(ct[((size_t)j * N_ + n1) * 64 + l31]);
      c1n = bf2f(ct[((size_t)j * N_ + n1) * 64 + 32 + l31]);
    }
    union { bf16x8 v_; u32 u[4]; } s0, s1;
    s0.u[0] = scale2_pk(xa.u[0], cv0); s0.u[1] = scale2_pk(xa.u[1], cv0);
    s0.u[2] = scale2_pk(xa.u[2], cv0); s0.u[3] = scale2_pk(xa.u[3], cv0);
    s1.u[0] = scale2_pk(xb.u[0], cv1); s1.u[1] = scale2_pk(xb.u[1], cv1);
    s1.u[2] = scale2_pk(xb.u[2], cv1); s1.u[3] = scale2_pk(xb.u[3], cv1);
    acc0 = __builtin_amdgcn_mfma_f32_32x32x16_bf16(wfr, s0.v_, acc0, 0, 0, 0);
    acc1 = __builtin_amdgcn_mfma_f32_32x32x16_bf16(wfr, s1.v_, acc1, 0, 0, 0);
    wfr = wfr_n; xa.v_ = xa_n.v_; xb.v_ = xb_n.v_; cv0 = c0n; cv1 = c1n;
  }
  #pragma unroll
  for (int r = 0; r < 16; ++r) {
    const int o = (r & 3) + 8 * (r >> 2) + 4 * h;
    red[wave][o * 64 + l31] = acc0[r];
    red[wave][o * 64 + 32 + l31] = acc1[r];
  }
  __syncthreads();
  float* dst = s_part + (size_t)split * (JO_ * B_) + (size_t)j * 32 * 64;
  #pragma unroll
  for (int k = 0; k < 8; ++k) {
    const int idx = tid + 256 * k;
    dst[idx] = red[0][idx] + red[1][idx] + red[2][idx] + red[3][idx];
  }
}

// ---------------------------------------------------------------------------
// SQUASH: replaces rs + r (2 launches -> 1). One (b,j) per wave (512 blocks
// x 4 waves = 2048). Lane o = l31; the h-halves split the nsplit partials;
// shfl combine + o-reduce. No atomics (round-10 lesson).
// v4 layout [j][h][b][16], element index g*4+rr == MFMA p-reg index.
// ---------------------------------------------------------------------------
__global__ __launch_bounds__(256) void squash_kernel(
    const float* __restrict__ s_part, float* __restrict__ v,
    u16* __restrict__ v4, float* __restrict__ out, int mode, float scale,
    int nsplit)
{
  const int tid = threadIdx.x;
  const int wave = tid >> 6, lane = tid & 63;
  const int l31 = lane & 31, h = lane >> 5;
  const int wid = blockIdx.x * 4 + wave;
  const int j = wid & 31, b = wid >> 5;
  const int o = l31;
  const int half = nsplit >> 1;
  float s = 0.f;
  const float* sp = s_part + (size_t)(j * 32 + o) * 64 + b
                  + (size_t)(h ? half : 0) * (JO_ * B_);
  for (int k = 0; k < half; ++k) s += sp[(size_t)k * (JO_ * B_)];
  const float st = (s + __shfl_xor(s, 32, 64)) * scale;   // combine h-halves
  float sq = st * st;
  #pragma unroll
  for (int m = 16; m >= 1; m >>= 1) sq += __shfl_xor(sq, m, 64);
  const float sc = sq / (1.f + sq) * rsqrtf(sq + 1e-8f);
  const float vv = sc * st;
  if (h == 0) {
    const size_t off = (size_t)b * JO_ + j * 32 + o;
    const int g = o >> 3, hh = (o >> 2) & 1, rr = o & 3;
    const size_t v4off = (((size_t)j * 2 + hh) * 64 + b) * 16 + g * 4 + rr;
    if (mode == 0)      { v[off] = vv; v4[v4off] = f2bf(vv); }
    else if (mode == 1) { v4[v4off] = f2bf(vv + v[off]); }
    else                { out[off] = vv; }
  }
}

// ---------------------------------------------------------------------------
// A kernel: round-8 verbatim. One n per block, 4 waves x 8 j-tiles,
// dot16 + 1-deep prefetch, unroll 1 under bounds(,4).
// ---------------------------------------------------------------------------
__global__ __launch_bounds__(256, 4) void a_kernel(
    const u16* __restrict__ xt, const u16* __restrict__ wb,
    const u16* __restrict__ v4, u16* __restrict__ ct)
{
  __shared__ float lgs[64][33];
  const int tid = threadIdx.x;
  const int wave = tid >> 6, lane = tid & 63;
  const int l31 = lane & 31, h = lane >> 5;
  const int n = blockIdx.x;
  const f32x16 zero16 = {0.f, 0.f, 0.f, 0.f, 0.f, 0.f, 0.f, 0.f,
                         0.f, 0.f, 0.f, 0.f, 0.f, 0.f, 0.f, 0.f};

  const bf16x8 x0 = *(const bf16x8*)(xt + ((size_t)n * 64 + l31) * 16 + h * 8);
  const bf16x8 x1 = *(const bf16x8*)(xt + ((size_t)n * 64 + 32 + l31) * 16 + h * 8);

  {
    const int t0 = wave * 8;
    bf16x8 wfr = *(const bf16x8*)(wb + ((size_t)n * JO_ + t0 * 32 + l31) * 16 + h * 8);
    const u16* pa = v4 + (((size_t)t0 * 2 + h) * 64 + l31) * 16;
    const u16* pb = v4 + (((size_t)t0 * 2 + h) * 64 + 32 + l31) * 16;
    uint4 va0 = *(const uint4*)(pa), va1 = *(const uint4*)(pa + 8);
    uint4 vb0 = *(const uint4*)(pb), vb1 = *(const uint4*)(pb + 8);

    #pragma unroll 1
    for (int tt = 0; tt < 8; ++tt) {
      const int t = wave * 8 + tt;
      bf16x8 wfr_n = wfr;
      uint4 va0n = va0, va1n = va1, vb0n = vb0, vb1n = vb1;
      if (tt + 1 < 8) {
        const int t1 = t + 1;
        wfr_n = *(const bf16x8*)(wb + ((size_t)n * JO_ + t1 * 32 + l31) * 16 + h * 8);
        const u16* qa = v4 + (((size_t)t1 * 2 + h) * 64 + l31) * 16;
        const u16* qb = v4 + (((size_t)t1 * 2 + h) * 64 + 32 + l31) * 16;
        va0n = *(const uint4*)(qa); va1n = *(const uint4*)(qa + 8);
        vb0n = *(const uint4*)(qb); vb1n = *(const uint4*)(qb + 8);
      }
      f32x16 p0 = __builtin_amdgcn_mfma_f32_32x32x16_bf16(wfr, x0, zero16, 0, 0, 0);
      f32x16 p1 = __builtin_amdgcn_mfma_f32_32x32x16_bf16(wfr, x1, zero16, 0, 0, 0);
      float s0 = dot16(p0, va0, va1);
      float s1 = dot16(p1, vb0, vb1);
      s0 += __shfl_xor(s0, 32, 64);
      s1 += __shfl_xor(s1, 32, 64);
      lgs[lane][t] = h ? s1 : s0;
      wfr = wfr_n; va0 = va0n; va1 = va1n; vb0 = vb0n; vb1 = vb1n;
    }
  }
  __syncthreads();

  if (tid < 64) {
    const int b = tid;
    float lv[32];
    float mx = -1e30f;
    #pragma unroll
    for (int t = 0; t < 32; ++t) { lv[t] = lgs[b][t]; mx = fmaxf(mx, lv[t]); }
    float sm = 0.f;
    #pragma unroll
    for (int t = 0; t < 32; ++t) { lv[t] = __expf(lv[t] - mx); sm += lv[t]; }
    const float inv = 1.f / sm;
    #pragma unroll
    for (int t = 0; t < 32; ++t) lgs[b][t] = lv[t] * inv;
  }
  __syncthreads();

  #pragma unroll
  for (int k = 0; k < 8; ++k) {
    const int idx = k * 256 + tid;
    const int t = idx >> 6, b = idx & 63;
    ct[((size_t)t * N_ + n) * 64 + b] = f2bf(lgs[b][t]);
  }
}

// ---------------------------------------------------------------------------
extern "C" void kernel_launch(void* const* d_in, const int* in_sizes, int n_in,
                              void* d_out, int out_size, void* d_ws, size_t ws_size,
                              hipStream_t stream) {
  const float* x = (const float*)d_in[0];
  const float* w = (const float*)d_in[1];
  float* out = (float*)d_out;
  char* ws = (char*)d_ws;
  // layout: wb 64MB | xt 4MB | s_part32 8MB | v0 256K | v4 128K |
  //         ct 8MB @78 | s_partSF 16MB @88
  u16*   wb       = (u16*)ws;
  u16*   xt       = (u16*)(ws + (size_t)64 * 1024 * 1024);
  float* s_part32 = (float*)(ws + (size_t)68 * 1024 * 1024);
  float* v0       = (float*)(ws + (size_t)76 * 1024 * 1024);
  u16*   v4       = (u16*)(ws + (size_t)76 * 1024 * 1024 + 262144);
  u16*   ct       = (u16*)(ws + (size_t)78 * 1024 * 1024);
  float* s_partSF = (float*)(ws + (size_t)88 * 1024 * 1024);

  dim3 wsfg(32, WSPLITS), sfg(32, SFSPLITS), b256(256);

  // 9 launches (was 12): each rs+r pair -> one squash
  xconv_kernel<<<dim3(512), b256, 0, stream>>>(x, xt);
  wsf_kernel<<<wsfg, b256, 0, stream>>>(w, wb, xt, s_part32);
  squash_kernel<<<dim3(512), b256, 0, stream>>>(s_part32, v0, v4, out, 0, 0.03125f, WSPLITS);
  a_kernel<<<dim3(2048), b256, 0, stream>>>(xt, wb, v4, ct);
  sf_kernel<<<sfg, b256, 0, stream>>>(xt, wb, ct, s_partSF);
  squash_kernel<<<dim3(512), b256, 0, stream>>>(s_partSF, v0, v4, out, 1, 1.0f, SFSPLITS);
  a_kernel<<<dim3(2048), b256, 0, stream>>>(xt, wb, v4, ct);
  sf_kernel<<<sfg, b256, 0, stream>>>(xt, wb, ct, s_partSF);
  squash_kernel<<<dim3(512), b256, 0, stream>>>(s_partSF, v0, v4, out, 2, 1.0f, SFSPLITS);
}

// Round 15
// 321.154 us; speedup vs baseline: 4.4245x; 1.0776x over previous
//
#include <hip/hip_runtime.h>
#include <hip/hip_bf16.h>

#define B_ 64
#define N_ 2048
#define I_ 16
#define J_ 32
#define O_ 32
#define JO_ 1024
#define WSPLITS 32
#define SFSPLITS 64

typedef __attribute__((ext_vector_type(8))) short bf16x8;
typedef __attribute__((ext_vector_type(16))) float f32x16;
typedef unsigned short u16;
typedef unsigned int u32;

__device__ __forceinline__ float bf2f(u16 u) {
  union { u32 i; float f; } c; c.i = ((u32)u) << 16; return c.f;
}
__device__ __forceinline__ u16 f2bf(float f) {
  union { float f; u32 i; } c; c.f = f;
  u32 r = (c.i + 0x7fffu + ((c.i >> 16) & 1u)) >> 16;
  return (u16)r;
}
// one-instruction pack of 2 f32 -> 2 bf16 (RNE)
__device__ __forceinline__ u32 pack2_pk(float lo, float hi) {
  u32 r;
  asm("v_cvt_pk_bf16_f32 %0, %1, %2" : "=v"(r) : "v"(lo), "v"(hi));
  return r;
}
// scale packed bf16 pair by cv
__device__ __forceinline__ u32 scale2_pk(u32 p, float cv) {
  union { u32 i; float f; } lo, hi;
  lo.i = p << 16; hi.i = p & 0xffff0000u;
  return pack2_pk(lo.f * cv, hi.f * cv);
}
// dot of 16 MFMA accs with 16 bf16 packed in two uint4 (index identity)
__device__ __forceinline__ float dot16(const f32x16& p, uint4 lo, uint4 hi) {
  const u32 w[8] = {lo.x, lo.y, lo.z, lo.w, hi.x, hi.y, hi.z, hi.w};
  float s = 0.f;
  #pragma unroll
  for (int k = 0; k < 8; ++k) {
    union { u32 i; float f; } a, b;
    a.i = w[k] << 16; b.i = w[k] & 0xffff0000u;
    s += p[2 * k] * a.f + p[2 * k + 1] * b.f;
  }
  return s;
}

// ---------------------------------------------------------------------------
// xconv: x f32 [b][n][i] -> xt bf16 [n][b][i]
// ---------------------------------------------------------------------------
__global__ __launch_bounds__(256) void xconv_kernel(
    const float* __restrict__ xf, u16* __restrict__ xt)
{
  const int idx = blockIdx.x * 256 + threadIdx.x;   // = b*2048 + n
  const int b = idx >> 11, n = idx & 2047;
  const float4* sp = (const float4*)(xf + (size_t)idx * 16);
  float4 f0 = sp[0], f1 = sp[1], f2 = sp[2], f3 = sp[3];
  uint4 d0, d1;
  d0.x = pack2_pk(f0.x, f0.y); d0.y = pack2_pk(f0.z, f0.w);
  d0.z = pack2_pk(f1.x, f1.y); d0.w = pack2_pk(f1.z, f1.w);
  d1.x = pack2_pk(f2.x, f2.y); d1.y = pack2_pk(f2.z, f2.w);
  d1.z = pack2_pk(f3.x, f3.y); d1.w = pack2_pk(f3.z, f3.w);
  uint4* dp = (uint4*)(xt + ((size_t)n * 64 + b) * 16);
  dp[0] = d0; dp[1] = d1;
}

// ---------------------------------------------------------------------------
// WSF kernel: fused wconv + sf iter-0. NEW: 2-deep named-stage rotation
// (unroll 1). Round-10 PMC showed VGPR=52 -> the old unroll-4 loop staged
// only ONE iteration's loads (~2.5KB in flight/CU vs 9KB needed for HBM BW
// -> ~30% BW on the 128MB cold w stream). Two stages double the in-flight
// loads; peak liveness ~95 VGPR < 128 cap (bounds(256,4)), no spill.
// ---------------------------------------------------------------------------
#define WSF_NPW 16

__global__ __launch_bounds__(256, 4) void wsf_kernel(
    const float* __restrict__ wf, u16* __restrict__ wb,
    const u16* __restrict__ xt, float* __restrict__ s_part)
{
  __shared__ float red[4][2048];   // 32 KB
  const int tid = threadIdx.x;
  const int wave = tid >> 6, lane = tid & 63;
  const int l31 = lane & 31, h = lane >> 5;
  const int j = blockIdx.x, split = blockIdx.y;
  const int n0 = (split * 4 + wave) * WSF_NPW;
  f32x16 acc0 = {0.f, 0.f, 0.f, 0.f, 0.f, 0.f, 0.f, 0.f,
                 0.f, 0.f, 0.f, 0.f, 0.f, 0.f, 0.f, 0.f};
  f32x16 acc1 = acc0;

  // per-lane bases; per-n strides: w 16384 floats (JO_*16), x 1024 u16
  const float* wbase = wf + ((size_t)n0 * JO_ + j * 32 + l31) * 16 + h * 8;
  const u16*   xbase = xt + (size_t)n0 * 1024 + l31 * 16 + h * 8;
  u16*         obase = wb + ((size_t)n0 * JO_ + j * 32 + l31) * 16 + h * 8;

  // prologue: stage A = iter 0, stage B = iter 1
  float4 wA0 = *(const float4*)(wbase), wA1 = *(const float4*)(wbase + 4);
  bf16x8 xA0 = *(const bf16x8*)(xbase), xA1 = *(const bf16x8*)(xbase + 512);
  float4 wB0 = *(const float4*)(wbase + 16384), wB1 = *(const float4*)(wbase + 16388);
  bf16x8 xB0 = *(const bf16x8*)(xbase + 1024), xB1 = *(const bf16x8*)(xbase + 1536);

  #pragma unroll 1
  for (int i = 0; i < WSF_NPW; i += 2) {
    // prefetch iter i+2 into A-temps (issued before A's dependent compute)
    float4 wA0n = wA0, wA1n = wA1; bf16x8 xA0n = xA0, xA1n = xA1;
    if (i + 2 < WSF_NPW) {
      const float* wp = wbase + (size_t)(i + 2) * 16384;
      const u16*   xp = xbase + (size_t)(i + 2) * 1024;
      wA0n = *(const float4*)(wp); wA1n = *(const float4*)(wp + 4);
      xA0n = *(const bf16x8*)(xp); xA1n = *(const bf16x8*)(xp + 512);
    }
    {   // consume A (iter i)
      union { uint4 u4; bf16x8 bv; } wd;
      wd.u4.x = pack2_pk(wA0.x, wA0.y); wd.u4.y = pack2_pk(wA0.z, wA0.w);
      wd.u4.z = pack2_pk(wA1.x, wA1.y); wd.u4.w = pack2_pk(wA1.z, wA1.w);
      *(uint4*)(obase + (size_t)i * 16384) = wd.u4;
      acc0 = __builtin_amdgcn_mfma_f32_32x32x16_bf16(wd.bv, xA0, acc0, 0, 0, 0);
      acc1 = __builtin_amdgcn_mfma_f32_32x32x16_bf16(wd.bv, xA1, acc1, 0, 0, 0);
    }
    wA0 = wA0n; wA1 = wA1n; xA0 = xA0n; xA1 = xA1n;
    // prefetch iter i+3 into B-temps
    float4 wB0n = wB0, wB1n = wB1; bf16x8 xB0n = xB0, xB1n = xB1;
    if (i + 3 < WSF_NPW) {
      const float* wp = wbase + (size_t)(i + 3) * 16384;
      const u16*   xp = xbase + (size_t)(i + 3) * 1024;
      wB0n = *(const float4*)(wp); wB1n = *(const float4*)(wp + 4);
      xB0n = *(const bf16x8*)(xp); xB1n = *(const bf16x8*)(xp + 512);
    }
    {   // consume B (iter i+1)
      union { uint4 u4; bf16x8 bv; } wd;
      wd.u4.x = pack2_pk(wB0.x, wB0.y); wd.u4.y = pack2_pk(wB0.z, wB0.w);
      wd.u4.z = pack2_pk(wB1.x, wB1.y); wd.u4.w = pack2_pk(wB1.z, wB1.w);
      *(uint4*)(obase + (size_t)(i + 1) * 16384) = wd.u4;
      acc0 = __builtin_amdgcn_mfma_f32_32x32x16_bf16(wd.bv, xB0, acc0, 0, 0, 0);
      acc1 = __builtin_amdgcn_mfma_f32_32x32x16_bf16(wd.bv, xB1, acc1, 0, 0, 0);
    }
    wB0 = wB0n; wB1 = wB1n; xB0 = xB0n; xB1 = xB1n;
  }
  #pragma unroll
  for (int r = 0; r < 16; ++r) {
    const int o = (r & 3) + 8 * (r >> 2) + 4 * h;
    red[wave][o * 64 + l31] = acc0[r];
    red[wave][o * 64 + 32 + l31] = acc1[r];
  }
  __syncthreads();
  float* dst = s_part + (size_t)split * (JO_ * B_) + (size_t)j * 32 * 64;
  #pragma unroll
  for (int k = 0; k < 8; ++k) {
    const int idx = tid + 256 * k;
    dst[idx] = red[0][idx] + red[1][idx] + red[2][idx] + red[3][idx];
  }
}

// ---------------------------------------------------------------------------
// SF kernel (iters 1,2): round-8 verbatim — 1-deep rotation, unroll 1,
// 64 splits (NPW=8). (Round-11's 4-deep batch was null: wb reads are
// L3-resident, short-latency -> MLP not binding here.)
// ---------------------------------------------------------------------------
#define SF_NPW 8

__global__ __launch_bounds__(256, 4) void sf_kernel(
    const u16* __restrict__ xt, const u16* __restrict__ wb,
    const u16* __restrict__ ct, float* __restrict__ s_part)
{
  __shared__ float red[4][2048];
  const int tid = threadIdx.x;
  const int wave = tid >> 6, lane = tid & 63;
  const int l31 = lane & 31, h = lane >> 5;
  const int j = blockIdx.x, split = blockIdx.y;
  const int n0 = (split * 4 + wave) * SF_NPW;
  f32x16 acc0 = {0.f, 0.f, 0.f, 0.f, 0.f, 0.f, 0.f, 0.f,
                 0.f, 0.f, 0.f, 0.f, 0.f, 0.f, 0.f, 0.f};
  f32x16 acc1 = acc0;

  bf16x8 wfr = *(const bf16x8*)(wb + ((size_t)n0 * JO_ + j * 32 + l31) * 16 + h * 8);
  union { bf16x8 v_; u32 u[4]; } xa, xb;
  xa.v_ = *(const bf16x8*)(xt + ((size_t)n0 * 64 + l31) * 16 + h * 8);
  xb.v_ = *(const bf16x8*)(xt + ((size_t)n0 * 64 + 32 + l31) * 16 + h * 8);
  float cv0 = bf2f(ct[((size_t)j * N_ + n0) * 64 + l31]);
  float cv1 = bf2f(ct[((size_t)j * N_ + n0) * 64 + 32 + l31]);

  #pragma unroll 1
  for (int i = 0; i < SF_NPW; ++i) {
    bf16x8 wfr_n = wfr;
    union { bf16x8 v_; u32 u[4]; } xa_n, xb_n;
    xa_n.v_ = xa.v_; xb_n.v_ = xb.v_;
    float c0n = cv0, c1n = cv1;
    if (i + 1 < SF_NPW) {
      const int n1 = n0 + i + 1;
      wfr_n = *(const bf16x8*)(wb + ((size_t)n1 * JO_ + j * 32 + l31) * 16 + h * 8);
      xa_n.v_ = *(const bf16x8*)(xt + ((size_t)n1 * 64 + l31) * 16 + h * 8);
      xb_n.v_ = *(const bf16x8*)(xt + ((size_t)n1 * 64 + 32 + l31) * 16 + h * 8);
      c0n = bf2f(ct[((size_t)j * N_ + n1) * 64 + l31]);
      c1n = bf2f(ct[((size_t)j * N_ + n1) * 64 + 32 + l31]);
    }
    union { bf16x8 v_; u32 u[4]; } s0, s1;
    s0.u[0] = scale2_pk(xa.u[0], cv0); s0.u[1] = scale2_pk(xa.u[1], cv0);
    s0.u[2] = scale2_pk(xa.u[2], cv0); s0.u[3] = scale2_pk(xa.u[3], cv0);
    s1.u[0] = scale2_pk(xb.u[0], cv1); s1.u[1] = scale2_pk(xb.u[1], cv1);
    s1.u[2] = scale2_pk(xb.u[2], cv1); s1.u[3] = scale2_pk(xb.u[3], cv1);
    acc0 = __builtin_amdgcn_mfma_f32_32x32x16_bf16(wfr, s0.v_, acc0, 0, 0, 0);
    acc1 = __builtin_amdgcn_mfma_f32_32x32x16_bf16(wfr, s1.v_, acc1, 0, 0, 0);
    wfr = wfr_n; xa.v_ = xa_n.v_; xb.v_ = xb_n.v_; cv0 = c0n; cv1 = c1n;
  }
  #pragma unroll
  for (int r = 0; r < 16; ++r) {
    const int o = (r & 3) + 8 * (r >> 2) + 4 * h;
    red[wave][o * 64 + l31] = acc0[r];
    red[wave][o * 64 + 32 + l31] = acc1[r];
  }
  __syncthreads();
  float* dst = s_part + (size_t)split * (JO_ * B_) + (size_t)j * 32 * 64;
  #pragma unroll
  for (int k = 0; k < 8; ++k) {
    const int idx = tid + 256 * k;
    dst[idx] = red[0][idx] + red[1][idx] + red[2][idx] + red[3][idx];
  }
}

// ---------------------------------------------------------------------------
// RS kernel: coalesced column-sum of nsplit partial buffers -> s_red.
// (Round-14's wave-gather squash regressed; coalesced rs+r restored.)
// ---------------------------------------------------------------------------
__global__ __launch_bounds__(256) void rs_kernel(
    const float* __restrict__ src, float* __restrict__ dst, int nsplit)
{
  const int idx = blockIdx.x * 256 + threadIdx.x;
  float s = 0.f;
  #pragma unroll 8
  for (int p = 0; p < nsplit; ++p) s += src[(size_t)p * (JO_ * B_) + idx];
  dst[idx] = s;
}

// ---------------------------------------------------------------------------
// R kernel: squash over o from s_red[jo][b] (256KB, L2-resident).
// v4 layout [j][h][b][16], element index g*4+rr == MFMA p-reg index.
// mode 0: v f32 + v4; 1: v4=f2bf(v+vprev); 2: out.
// ---------------------------------------------------------------------------
__global__ __launch_bounds__(64) void r_kernel(
    const float* __restrict__ s_red, float* __restrict__ v,
    const float* __restrict__ vprev, u16* __restrict__ v4,
    float* __restrict__ out, int mode, float scale)
{
  const int tid = threadIdx.x;
  const int jj = tid >> 5, o = tid & 31;
  const int b = blockIdx.x >> 4, jg = blockIdx.x & 15;
  const int j = jg * 2 + jj;
  const float s = s_red[(size_t)(j * 32 + o) * 64 + b] * scale;
  float sq = s * s;
  #pragma unroll
  for (int m = 16; m >= 1; m >>= 1) sq += __shfl_xor(sq, m, 64);
  const float sc = sq / (1.f + sq) * rsqrtf(sq + 1e-8f);
  const float vv = sc * s;
  const size_t off = (size_t)b * JO_ + j * 32 + o;
  const int g = o >> 3, hh = (o >> 2) & 1, rr = o & 3;
  const size_t v4off = (((size_t)j * 2 + hh) * 64 + b) * 16 + g * 4 + rr;
  if (mode == 0) { v[off] = vv; v4[v4off] = f2bf(vv); }
  else if (mode == 1) { v4[v4off] = f2bf(vv + vprev[off]); }
  else { out[off] = vv; }
}

// ---------------------------------------------------------------------------
// A kernel: round-8 verbatim. One n per block, 4 waves x 8 j-tiles,
// dot16 + 1-deep prefetch, unroll 1 under bounds(,4).
// ---------------------------------------------------------------------------
__global__ __launch_bounds__(256, 4) void a_kernel(
    const u16* __restrict__ xt, const u16* __restrict__ wb,
    const u16* __restrict__ v4, u16* __restrict__ ct)
{
  __shared__ float lgs[64][33];
  const int tid = threadIdx.x;
  const int wave = tid >> 6, lane = tid & 63;
  const int l31 = lane & 31, h = lane >> 5;
  const int n = blockIdx.x;
  const f32x16 zero16 = {0.f, 0.f, 0.f, 0.f, 0.f, 0.f, 0.f, 0.f,
                         0.f, 0.f, 0.f, 0.f, 0.f, 0.f, 0.f, 0.f};

  const bf16x8 x0 = *(const bf16x8*)(xt + ((size_t)n * 64 + l31) * 16 + h * 8);
  const bf16x8 x1 = *(const bf16x8*)(xt + ((size_t)n * 64 + 32 + l31) * 16 + h * 8);

  {
    const int t0 = wave * 8;
    bf16x8 wfr = *(const bf16x8*)(wb + ((size_t)n * JO_ + t0 * 32 + l31) * 16 + h * 8);
    const u16* pa = v4 + (((size_t)t0 * 2 + h) * 64 + l31) * 16;
    const u16* pb = v4 + (((size_t)t0 * 2 + h) * 64 + 32 + l31) * 16;
    uint4 va0 = *(const uint4*)(pa), va1 = *(const uint4*)(pa + 8);
    uint4 vb0 = *(const uint4*)(pb), vb1 = *(const uint4*)(pb + 8);

    #pragma unroll 1
    for (int tt = 0; tt < 8; ++tt) {
      const int t = wave * 8 + tt;
      bf16x8 wfr_n = wfr;
      uint4 va0n = va0, va1n = va1, vb0n = vb0, vb1n = vb1;
      if (tt + 1 < 8) {
        const int t1 = t + 1;
        wfr_n = *(const bf16x8*)(wb + ((size_t)n * JO_ + t1 * 32 + l31) * 16 + h * 8);
        const u16* qa = v4 + (((size_t)t1 * 2 + h) * 64 + l31) * 16;
        const u16* qb = v4 + (((size_t)t1 * 2 + h) * 64 + 32 + l31) * 16;
        va0n = *(const uint4*)(qa); va1n = *(const uint4*)(qa + 8);
        vb0n = *(const uint4*)(qb); vb1n = *(const uint4*)(qb + 8);
      }
      f32x16 p0 = __builtin_amdgcn_mfma_f32_32x32x16_bf16(wfr, x0, zero16, 0, 0, 0);
      f32x16 p1 = __builtin_amdgcn_mfma_f32_32x32x16_bf16(wfr, x1, zero16, 0, 0, 0);
      float s0 = dot16(p0, va0, va1);
      float s1 = dot16(p1, vb0, vb1);
      s0 += __shfl_xor(s0, 32, 64);
      s1 += __shfl_xor(s1, 32, 64);
      lgs[lane][t] = h ? s1 : s0;
      wfr = wfr_n; va0 = va0n; va1 = va1n; vb0 = vb0n; vb1 = vb1n;
    }
  }
  __syncthreads();

  if (tid < 64) {
    const int b = tid;
    float lv[32];
    float mx = -1e30f;
    #pragma unroll
    for (int t = 0; t < 32; ++t) { lv[t] = lgs[b][t]; mx = fmaxf(mx, lv[t]); }
    float sm = 0.f;
    #pragma unroll
    for (int t = 0; t < 32; ++t) { lv[t] = __expf(lv[t] - mx); sm += lv[t]; }
    const float inv = 1.f / sm;
    #pragma unroll
    for (int t = 0; t < 32; ++t) lgs[b][t] = lv[t] * inv;
  }
  __syncthreads();

  #pragma unroll
  for (int k = 0; k < 8; ++k) {
    const int idx = k * 256 + tid;
    const int t = idx >> 6, b = idx & 63;
    ct[((size_t)t * N_ + n) * 64 + b] = f2bf(lgs[b][t]);
  }
}

// ---------------------------------------------------------------------------
extern "C" void kernel_launch(void* const* d_in, const int* in_sizes, int n_in,
                              void* d_out, int out_size, void* d_ws, size_t ws_size,
                              hipStream_t stream) {
  const float* x = (const float*)d_in[0];
  const float* w = (const float*)d_in[1];
  float* out = (float*)d_out;
  char* ws = (char*)d_ws;
  // layout: wb 64MB | xt 4MB | s_part32 8MB | s_red 256K | v0 256K | v4 128K
  //         | ct 8MB @78 | s_partSF 16MB @88
  u16*   wb       = (u16*)ws;
  u16*   xt       = (u16*)(ws + (size_t)64 * 1024 * 1024);
  float* s_part32 = (float*)(ws + (size_t)68 * 1024 * 1024);
  float* s_red    = (float*)(ws + (size_t)76 * 1024 * 1024);
  float* v0       = (float*)(ws + (size_t)76 * 1024 * 1024 + 262144);
  u16*   v4       = (u16*)(ws + (size_t)76 * 1024 * 1024 + 2 * 262144);
  u16*   ct       = (u16*)(ws + (size_t)78 * 1024 * 1024);
  float* s_partSF = (float*)(ws + (size_t)88 * 1024 * 1024);

  dim3 wsfg(32, WSPLITS), sfg(32, SFSPLITS), b256(256);
  dim3 ag(2048);
  dim3 rsg(256), rsb(256);
  dim3 rg(1024), rb(64);

  xconv_kernel<<<dim3(512), b256, 0, stream>>>(x, xt);
  // iter 0: fused wconv + uniform-c accumulate (c folded as 1/32 in r)
  wsf_kernel<<<wsfg, b256, 0, stream>>>(w, wb, xt, s_part32);
  rs_kernel<<<rsg, rsb, 0, stream>>>(s_part32, s_red, WSPLITS);
  r_kernel<<<rg, rb, 0, stream>>>(s_red, v0, v0, v4, out, 0, 0.03125f);
  // iter 1
  a_kernel<<<ag, b256, 0, stream>>>(xt, wb, v4, ct);
  sf_kernel<<<sfg, b256, 0, stream>>>(xt, wb, ct, s_partSF);
  rs_kernel<<<rsg, rsb, 0, stream>>>(s_partSF, s_red, SFSPLITS);
  r_kernel<<<rg, rb, 0, stream>>>(s_red, v0, v0, v4, out, 1, 1.0f);
  // iter 2 (logits = pred . (v0+v1) via v4)
  a_kernel<<<ag, b256, 0, stream>>>(xt, wb, v4, ct);
  sf_kernel<<<sfg, b256, 0, stream>>>(xt, wb, ct, s_partSF);
  rs_kernel<<<rsg, rsb, 0, stream>>>(s_partSF, s_red, SFSPLITS);
  r_kernel<<<rg, rb, 0, stream>>>(s_red, v0, v0, v4, out, 2, 1.0f);
}